// Round 16
// baseline (238.474 us; speedup 1.0000x reference)
//
#include <hip/hip_runtime.h>
#include <cstdint>
#include <cstddef>

typedef unsigned short u16;
typedef unsigned int   u32;
typedef long long      i64;

#define N_NODES 50000
#define N_EDGES 1600000
#define DIM     128
#define NHEADS  4
#define NEG_SLOPE 0.2f
#define CAP     64          // per-node slab (max deg ~58 for Binom(1.6M,1/50k); exact ovf path)
#define NB      782         // buckets of 64 nodes: bucket = r >> 6 (50000/64 -> 782)
#define SB      512         // hist/scatter blocks; EPB = E/SB = 3125 exact
#define EPB     (N_EDGES / SB)
#define PROJ_BLOCKS ((N_NODES + 63) / 64)   // 782

typedef __attribute__((ext_vector_type(8))) short bf16x8;
typedef __attribute__((ext_vector_type(4))) float f32x4;

__device__ __forceinline__ float b2f(u16 u) {
    union { u32 u; float f; } v; v.u = ((u32)u) << 16; return v.f;
}
__device__ __forceinline__ float bflo(u32 w) {
    union { u32 u; float f; } v; v.u = w << 16; return v.f;
}
__device__ __forceinline__ float bfhi(u32 w) {
    union { u32 u; float f; } v; v.u = w & 0xffff0000u; return v.f;
}
__device__ __forceinline__ u16 f2b(float f) {
    union { float f; u32 u; } v; v.f = f;
    u32 u = v.u;
    u32 r = (u + 0x7fffu + ((u >> 16) & 1u)) >> 16;
    return (u16)r;
}
__device__ __forceinline__ float leaky(float v) {
    return v >= 0.f ? v : NEG_SLOPE * v;
}
// f=1: fp32 storage; f=0: packed bf16
__device__ __forceinline__ float fload(const void* p, int f, int idx) {
    return f ? ((const float*)p)[idx] : b2f(((const u16*)p)[idx]);
}
// edge_index stored (2, E) row-major: elem[e]=row_e, elem[E+e]=col_e
__device__ __forceinline__ int eload(const void* ei, int f64, int idx) {
    return f64 ? (int)((const i64*)ei)[idx] : ((const int*)ei)[idx];
}

// ---------------------------------------------------------------------------
// storage detection helpers (validated; run per-block in canon)
// ---------------------------------------------------------------------------
__device__ __forceinline__ int fp32_vote(const u32* p, int K, int lane) {
    int bad = 0;
    for (int i = lane; i < K; i += 64) {
        const u32 w = p[i];
        const u16 lo = (u16)(w & 0xffff);
        const float v = b2f(lo);
        if (lo == 0 || !(fabsf(v) < 1e4f)) ++bad;
    }
    #pragma unroll
    for (int off = 32; off > 0; off >>= 1) bad += __shfl_down(bad, off);
    return bad;
}

__device__ __forceinline__ void compute_flags(
    const u32* x, const u32* wq, const u32* wk, const u32* wl,
    const u32* bl, const u32* ei, int* lf)
{
    const int t = threadIdx.x;
    if (t < 64) {
        const int lane = t;
        int b;
        b = fp32_vote(x,  256, lane); if (lane == 0) lf[0] = (b > 64);
        b = fp32_vote(wq, 128, lane); if (lane == 0) lf[1] = (b > 32);
        b = fp32_vote(wk, 128, lane); if (lane == 0) lf[2] = (b > 32);
        b = fp32_vote(wl, 256, lane); if (lane == 0) lf[3] = (b > 64);
        b = fp32_vote(bl,  64, lane); if (lane == 0) lf[4] = (b > 16);
        int z = 0;
        for (int i = lane; i < 256; i += 64)
            if (ei[2 * i + 1] == 0) ++z;
        #pragma unroll
        for (int off = 32; off > 0; off >>= 1) z += __shfl_down(z, off);
        if (lane == 0) lf[5] = (z > 128);
    }
    __syncthreads();
}

// B-image layout helper: value of stacked-B row/col (row in [0,160))
__device__ __forceinline__ float bimg_val(
    int row, int col, const void* Wq, const void* Wk, const void* Wl,
    const int* lf)
{
    if (row < 128)      return fload(Wl, lf[3], row * 128 + col);
    if (row < 132)      return fload(Wq, lf[1], (row - 128) * 128 + col);
    if (row < 136)      return fload(Wk, lf[2], (row - 132) * 128 + col);
    if (row < 144)      return 0.f;
    if (row < 148) { const float w = fload(Wq, lf[1], (row - 144) * 128 + col);
                     return w - b2f(f2b(w)); }
    if (row < 152) { const float w = fload(Wk, lf[2], (row - 148) * 128 + col);
                     return w - b2f(f2b(w)); }
    return 0.f;
}

// ---------------------------------------------------------------------------
// K canon v4: detection + ovf_cnt/done zeroing folded in (validated r14).
// ---------------------------------------------------------------------------
#define W_TOTAL (512 + 512 + 16384 + 128)
#define PACKB_JOBS (160 * 64)            // u32 words of the B image
__global__ __launch_bounds__(256) void canon_w_kernel(
    const void* __restrict__ x,  const void* __restrict__ ei,
    const void* __restrict__ Wq, const void* __restrict__ Wk,
    const void* __restrict__ Wl, const void* __restrict__ bl,
    int* __restrict__ flags, int* __restrict__ ovf_cnt,
    int* __restrict__ done,
    float* __restrict__ wf, u32* __restrict__ wbp)
{
    __shared__ int lf[8];
    compute_flags((const u32*)x, (const u32*)Wq, (const u32*)Wk,
                  (const u32*)Wl, (const u32*)bl, (const u32*)ei, lf);
    const int i = blockIdx.x * 256 + threadIdx.x;
    if (blockIdx.x == 0 && threadIdx.x == 0) {
        #pragma unroll
        for (int k = 0; k < 6; ++k) flags[k] = lf[k];
        *ovf_cnt = 0;
        *done = 0;
    }
    if (i < W_TOTAL) {
        const void* src; int j, f;
        if (i < 512)         { src = Wq; j = i;         f = lf[1]; }
        else if (i < 1024)   { src = Wk; j = i - 512;   f = lf[2]; }
        else if (i < 17408)  { src = Wl; j = i - 1024;  f = lf[3]; }
        else                 { src = bl; j = i - 17408; f = lf[4]; }
        wf[i] = fload(src, f, j);
        return;
    }
    const int w = i - W_TOTAL;
    if (w >= PACKB_JOBS) return;
    const int row  = w >> 6;
    const int col0 = (w & 63) * 2;
    const float v0 = bimg_val(row, col0,     Wq, Wk, Wl, lf);
    const float v1 = bimg_val(row, col0 + 1, Wq, Wk, Wl, lf);
    const int scol0 = col0 ^ ((row & 7) << 3);
    wbp[row * 64 + (scol0 >> 1)] = (u32)f2b(v0) | ((u32)f2b(v1) << 16);
}

// ---------------------------------------------------------------------------
// K1+S1 PACKED: blocks [0, PROJ_BLOCKS) = MFMA proj; rest = hist+pack
//   (validated r15).
// ---------------------------------------------------------------------------
__global__ __launch_bounds__(256) void proj_hist_kernel(
    const void* __restrict__ x, const void* __restrict__ ei,
    const int* __restrict__ flags,
    const float* __restrict__ wf, const u32* __restrict__ wbp,
    u16* __restrict__ h_projb, float* __restrict__ h_q,
    float* __restrict__ k_act,
    u32* __restrict__ rc32, int* __restrict__ hist)
{
    __shared__ __align__(16) char smem[160 * 128 * 2];   // 40 KB, aliased
    const int t = threadIdx.x;

    if (blockIdx.x >= PROJ_BLOCKS) {
        // ---------------- hist branch ----------------
        int* h = (int*)smem;
        const int blk = blockIdx.x - PROJ_BLOCKS;
        for (int i = t; i < NB; i += 256) h[i] = 0;
        __syncthreads();
        const int fe = flags[5];
        const int e0 = blk * EPB;
        const int e1 = min(e0 + EPB, N_EDGES);
        for (int e = e0 + t; e < e1; e += 256) {
            const int r = eload(ei, fe, e);
            const int c = eload(ei, fe, N_EDGES + e);
            rc32[e] = ((u32)r << 16) | (u32)c;
            atomicAdd(&h[r >> 6], 1);
        }
        __syncthreads();
        for (int i = t; i < NB; i += 256) hist[blk * NB + i] = h[i];
        return;
    }

    // ---------------- proj branch (validated r12) ----------------
    u16* sB   = (u16*)smem;
    u32* sB32 = (u32*)smem;
    const int w  = t >> 6;
    const int l  = t & 63;
    const int lr = l & 15;               // row/col within 16-tile
    const int lg = l >> 4;               // k-group / m-group
    const int Mb = blockIdx.x * 64 + w * 16;
    const float* bl = wf + 17408;

    #pragma unroll 8
    for (int i = t; i < 160 * 64; i += 256) sB32[i] = wbp[i];
    __syncthreads();

    const int fx = flags[0];
    f32x4 acc[9];
    #pragma unroll
    for (int tt = 0; tt < 8; ++tt) {
        const float bias = bl[tt * 16 + lr];
        acc[tt][0] = bias; acc[tt][1] = bias; acc[tt][2] = bias; acc[tt][3] = bias;
    }
    acc[8][0] = 0.f; acc[8][1] = 0.f; acc[8][2] = 0.f; acc[8][3] = 0.f;

    const int arow = min(Mb + lr, N_NODES - 1);

    #pragma unroll
    for (int kk = 0; kk < 4; ++kk) {
        const int kbase = kk * 32 + lg * 8;
        bf16x8 ahi, alo;
        if (fx == 0) {
            ahi = *(const bf16x8*)((const u16*)x + (size_t)arow * 128 + kbase);
            #pragma unroll
            for (int i = 0; i < 8; ++i) alo[i] = 0;
        } else {
            const float* xf = (const float*)x + (size_t)arow * 128 + kbase;
            const float4 v0 = *(const float4*)xf;
            const float4 v1 = *(const float4*)(xf + 4);
            const float vv[8] = {v0.x, v0.y, v0.z, v0.w, v1.x, v1.y, v1.z, v1.w};
            #pragma unroll
            for (int i = 0; i < 8; ++i) {
                const u16 h = f2b(vv[i]);
                ahi[i] = (short)h;
                alo[i] = (short)f2b(vv[i] - b2f(h));
            }
        }
        #pragma unroll
        for (int tt = 0; tt < 9; ++tt) {
            const int row = tt * 16 + lr;
            const bf16x8 b = *(const bf16x8*)&sB[row * 128 + (kbase ^ ((row & 7) << 3))];
            acc[tt] = __builtin_amdgcn_mfma_f32_16x16x32_bf16(ahi, b, acc[tt], 0, 0, 0);
            if (fx)
                acc[tt] = __builtin_amdgcn_mfma_f32_16x16x32_bf16(alo, b, acc[tt], 0, 0, 0);
        }
        {   // qk lo-tile (rows 144-159) accumulates into acc[8]
            const int row = 144 + lr;
            const bf16x8 b9 = *(const bf16x8*)&sB[row * 128 + (kbase ^ ((row & 7) << 3))];
            acc[8] = __builtin_amdgcn_mfma_f32_16x16x32_bf16(ahi, b9, acc[8], 0, 0, 0);
        }
    }

    #pragma unroll
    for (int tt = 0; tt < 8; ++tt) {
        const int o = tt * 16 + lr;
        #pragma unroll
        for (int j = 0; j < 4; ++j) {
            const int n = Mb + lg * 4 + j;
            if (n < N_NODES) h_projb[(size_t)n * 128 + o] = f2b(acc[tt][j]);
        }
    }
    #pragma unroll
    for (int j = 0; j < 4; ++j) {
        const int n = Mb + lg * 4 + j;
        if (n < N_NODES) {
            if (lr < 4)      h_q[n * 4 + lr] = acc[8][j];
            else if (lr < 8) k_act[n * 4 + (lr - 4)] = leaky(acc[8][j]);
        }
    }
}

// ---------------------------------------------------------------------------
// S2 v3: per-bucket scan over 512 block-counts (XCD-grouped order, r12) +
//   scanB FOLDED IN via last-block pattern: the block whose atomicAdd(done)
//   returns NB-1 knows all btot[] writes are complete (it IS the last
//   finisher — no spin, no co-residency assumption; threadfence gives
//   device-scope visibility per G16) and computes btbase in-kernel.
// ---------------------------------------------------------------------------
__device__ __forceinline__ int gperm(int j) {
    return ((j & 63) << 3) | (j >> 6);
}
__global__ __launch_bounds__(256) void scanA_kernel(
    int* __restrict__ hist, int* __restrict__ btot,
    int* __restrict__ btbase, int* __restrict__ done)
{
    __shared__ int part[256];
    __shared__ int amlast;
    const int b = blockIdx.x;
    const int t = threadIdx.x;
    const int b0 = gperm(2 * t), b1 = gperm(2 * t + 1);
    const int v0 = hist[b0 * NB + b];
    const int v1 = hist[b1 * NB + b];
    part[t] = v0 + v1;
    __syncthreads();
    for (int off = 1; off < 256; off <<= 1) {
        const int v = (t >= off) ? part[t - off] : 0;
        __syncthreads();
        part[t] += v;
        __syncthreads();
    }
    const int pre = part[t] - (v0 + v1);
    hist[b0 * NB + b] = pre;
    hist[b1 * NB + b] = pre + v0;
    if (t == 255) {
        btot[b] = part[255];
        __threadfence();                       // publish btot[b] device-wide
        const int v = atomicAdd(done, 1);
        amlast = (v == NB - 1);
    }
    __syncthreads();
    if (!amlast) return;
    // ---- scanB folded in: exclusive scan of btot[0..NB) -> btbase ----
    __threadfence();                           // acquire others' btot writes
    int v4[4];
    int s = 0;
    #pragma unroll
    for (int k = 0; k < 4; ++k) {
        const int idx = t * 4 + k;
        v4[k] = (idx < NB) ? btot[idx] : 0;
        s += v4[k];
    }
    part[t] = s;
    __syncthreads();
    for (int off = 1; off < 256; off <<= 1) {
        const int v = (t >= off) ? part[t - off] : 0;
        __syncthreads();
        part[t] += v;
        __syncthreads();
    }
    int run = part[t] - s;
    #pragma unroll
    for (int k = 0; k < 4; ++k) {
        const int idx = t * 4 + k;
        if (idx < NB) btbase[idx] = run;
        run += v4[k];
    }
    if (t == 255) btbase[NB] = part[255];
}

// ---------------------------------------------------------------------------
// S4: scatter to bucket-sorted array with EXACT precomputed offsets.
// ---------------------------------------------------------------------------
__global__ __launch_bounds__(256) void scatter_kernel(
    const u32* __restrict__ rc32, const int* __restrict__ hist,
    const int* __restrict__ btbase, u32* __restrict__ sorted)
{
    __shared__ int lbase[NB];
    const int t = threadIdx.x, blk = blockIdx.x;
    for (int i = t; i < NB; i += 256)
        lbase[i] = btbase[i] + hist[blk * NB + i];
    __syncthreads();
    const int e0 = blk * EPB;
    const int e1 = min(e0 + EPB, N_EDGES);
    for (int e = e0 + t; e < e1; e += 256) {
        const u32 rc = rc32[e];
        const int p = atomicAdd(&lbase[rc >> 22], 1);   // bucket = r>>6 = rc>>22
        sorted[p] = rc;
    }
}

// ---------------------------------------------------------------------------
// S5 v3: per-bucket slab build + fused q_agg (post-fill shfl gather,
//   validated r14).
// ---------------------------------------------------------------------------
__global__ __launch_bounds__(256) void slab_kernel(
    const u32* __restrict__ sorted, const int* __restrict__ btbase,
    const float* __restrict__ h_q,
    int* __restrict__ deg, u16* __restrict__ csr_col,
    int* __restrict__ ovf_cnt, u32* __restrict__ ovf,
    float* __restrict__ q_agg)
{
    __shared__ int   cnt[64];
    __shared__ float qov[64][4];         // overflow-only accumulator (rare)
    const int t = threadIdx.x, b = blockIdx.x;
    if (t < 64) {
        cnt[t] = 0;
        qov[t][0] = 0.f; qov[t][1] = 0.f; qov[t][2] = 0.f; qov[t][3] = 0.f;
    }
    __syncthreads();
    const int s0 = btbase[b], s1 = btbase[b + 1];
    for (int i = s0 + t; i < s1; i += 256) {
        const u32 rc = sorted[i];
        const int r  = (int)(rc >> 16);
        const int c  = (int)(rc & 0xffffu);
        const int rl = r & 63;
        const int p = atomicAdd(&cnt[rl], 1);
        if (p < CAP) {
            csr_col[r * CAP + p] = (u16)c;
        } else {                          // rare-path: exact
            const int k = atomicAdd(ovf_cnt, 1);
            ovf[k] = rc;
            const float4 q = ((const float4*)h_q)[c];
            atomicAdd(&qov[rl][0], q.x);
            atomicAdd(&qov[rl][1], q.y);
            atomicAdd(&qov[rl][2], q.z);
            atomicAdd(&qov[rl][3], q.w);
        }
    }
    __syncthreads();
    // post-fill per-node q_agg gather: 4 threads per node, shfl-reduce
    const int nl = t >> 2;               // node-local 0..63
    const int ql = t & 3;                // quarter within node group
    const int n  = b * 64 + nl;
    float sx = 0.f, sy = 0.f, sz = 0.f, sw = 0.f;
    int d = 0;
    if (n < N_NODES) {
        d = cnt[nl];
        const int prim = min(d, CAP);
        for (int j = ql; j < prim; j += 4) {
            const int c = csr_col[n * CAP + j];
            const float4 q = ((const float4*)h_q)[c];
            sx += q.x; sy += q.y; sz += q.z; sw += q.w;
        }
    }
    sx += __shfl_down(sx, 2); sx += __shfl_down(sx, 1);
    sy += __shfl_down(sy, 2); sy += __shfl_down(sy, 1);
    sz += __shfl_down(sz, 2); sz += __shfl_down(sz, 1);
    sw += __shfl_down(sw, 2); sw += __shfl_down(sw, 1);
    if (n < N_NODES && ql == 0) {
        deg[n] = d;
        ((float4*)q_agg)[n] = make_float4(
            sx + qov[nl][0], sy + qov[nl][1], sz + qov[nl][2], sw + qov[nl][3]);
    }
}

// ---------------------------------------------------------------------------
// K7: fused softmax + weighted aggregation -> out fp32 (validated r6-r15)
// ---------------------------------------------------------------------------
__global__ __launch_bounds__(256) void attn_kernel(
    const int* __restrict__ deg_a, const u16* __restrict__ csr_col,
    const int* __restrict__ ovf_cnt, const u32* __restrict__ ovf,
    const float* __restrict__ k_act, const float* __restrict__ q_agg,
    const u16* __restrict__ h_projb, float* __restrict__ out)
{
    const int wave = threadIdx.x >> 6, lane = threadIdx.x & 63;
    const int n = blockIdx.x * 4 + wave;
    if (n >= N_NODES) return;
    const int deg = deg_a[n];
    const int prim = min(deg, CAP);
    const float4 k4 = ((const float4*)k_act)[n];

    // ---- pass A: scores (slot = lane), split max/sum reduction ----
    int cA = 0;
    float sA0 = -1e30f, sA1 = -1e30f, sA2 = -1e30f, sA3 = -1e30f;
    if (lane < prim) {
        cA = csr_col[n * CAP + lane];
        const float4 q = ((const float4*)q_agg)[cA];
        sA0 = k4.x * q.x; sA1 = k4.y * q.y;
        sA2 = k4.z * q.z; sA3 = k4.w * q.w;
    }
    float m0 = sA0, m1 = sA1, m2 = sA2, m3 = sA3;
    const int ovf_n = (deg > CAP) ? *ovf_cnt : 0;
    for (int i = lane; i < ovf_n; i += 64) {
        const u32 pk = ovf[i];
        if ((int)(pk >> 16) != n) continue;
        const float4 q = ((const float4*)q_agg)[pk & 0xffffu];
        m0 = fmaxf(m0, k4.x * q.x); m1 = fmaxf(m1, k4.y * q.y);
        m2 = fmaxf(m2, k4.z * q.z); m3 = fmaxf(m3, k4.w * q.w);
    }
    #pragma unroll
    for (int off = 32; off > 0; off >>= 1) {
        m0 = fmaxf(m0, __shfl_xor(m0, off));
        m1 = fmaxf(m1, __shfl_xor(m1, off));
        m2 = fmaxf(m2, __shfl_xor(m2, off));
        m3 = fmaxf(m3, __shfl_xor(m3, off));
    }
    const float e0 = __expf(sA0 - m0), e1 = __expf(sA1 - m1);
    const float e2 = __expf(sA2 - m2), e3 = __expf(sA3 - m3);
    float u0 = e0, u1 = e1, u2 = e2, u3 = e3;
    for (int i = lane; i < ovf_n; i += 64) {
        const u32 pk = ovf[i];
        if ((int)(pk >> 16) != n) continue;
        const float4 q = ((const float4*)q_agg)[pk & 0xffffu];
        u0 += __expf(k4.x * q.x - m0); u1 += __expf(k4.y * q.y - m1);
        u2 += __expf(k4.z * q.z - m2); u3 += __expf(k4.w * q.w - m3);
    }
    #pragma unroll
    for (int off = 32; off > 0; off >>= 1) {
        u0 += __shfl_xor(u0, off); u1 += __shfl_xor(u1, off);
        u2 += __shfl_xor(u2, off); u3 += __shfl_xor(u3, off);
    }
    const float r0 = 0.25f / (u0 + 1e-8f), r1 = 0.25f / (u1 + 1e-8f);
    const float r2 = 0.25f / (u2 + 1e-8f), r3 = 0.25f / (u3 + 1e-8f);
    const float a_s = e0 * r0 + e1 * r1 + e2 * r2 + e3 * r3;  // lane's alpha

    // ---- pass B: quad-edge broadcast accumulate ----
    const int sub4 = lane & 15;          // dim group: dims 8*sub4 .. 8*sub4+7
    const int eh4  = lane >> 4;          // which edge of the quad (0..3)
    float acc[8] = {0.f, 0.f, 0.f, 0.f, 0.f, 0.f, 0.f, 0.f};
    const uint4* hp4 = (const uint4*)h_projb;   // row stride = 16 uint4 (256 B)

    #pragma unroll 4
    for (int j = 0; j < prim; j += 4) {
        const int   c = __shfl(cA,  j + eh4);
        const float a = __shfl(a_s, j + eh4);
        const uint4 w = hp4[(size_t)c * 16 + sub4];
        acc[0] = fmaf(a, bflo(w.x), acc[0]);
        acc[1] = fmaf(a, bfhi(w.x), acc[1]);
        acc[2] = fmaf(a, bflo(w.y), acc[2]);
        acc[3] = fmaf(a, bfhi(w.y), acc[3]);
        acc[4] = fmaf(a, bflo(w.z), acc[4]);
        acc[5] = fmaf(a, bfhi(w.z), acc[5]);
        acc[6] = fmaf(a, bflo(w.w), acc[6]);
        acc[7] = fmaf(a, bfhi(w.w), acc[7]);
    }
    for (int base = 0; base < ovf_n; base += 64) {
        const int i = base + lane;
        int   c_s = 0;
        float a_v = 0.f;
        if (i < ovf_n) {
            const u32 pk = ovf[i];
            if ((int)(pk >> 16) == n) {
                c_s = (int)(pk & 0xffffu);
                const float4 q = ((const float4*)q_agg)[c_s];
                a_v = __expf(k4.x * q.x - m0) * r0 + __expf(k4.y * q.y - m1) * r1
                    + __expf(k4.z * q.z - m2) * r2 + __expf(k4.w * q.w - m3) * r3;
            }
        }
        const int cnt = min(64, ovf_n - base);
        for (int j = 0; j < cnt; j += 4) {
            const int   jj = j + eh4;
            const int   c = __shfl(c_s, jj);      // lanes past cnt hold a_v=0
            const float a = __shfl(a_v, jj);
            const uint4 w = hp4[(size_t)c * 16 + sub4];
            acc[0] = fmaf(a, bflo(w.x), acc[0]);
            acc[1] = fmaf(a, bfhi(w.x), acc[1]);
            acc[2] = fmaf(a, bflo(w.y), acc[2]);
            acc[3] = fmaf(a, bfhi(w.y), acc[3]);
            acc[4] = fmaf(a, bflo(w.z), acc[4]);
            acc[5] = fmaf(a, bfhi(w.z), acc[5]);
            acc[6] = fmaf(a, bflo(w.w), acc[6]);
            acc[7] = fmaf(a, bfhi(w.w), acc[7]);
        }
    }
    #pragma unroll
    for (int d = 0; d < 8; ++d) {
        acc[d] += __shfl_down(acc[d], 32);
        acc[d] += __shfl_down(acc[d], 16);
    }
    if (eh4 == 0) {
        ((float4*)out)[(size_t)n * 32 + sub4 * 2] =
            make_float4(leaky(acc[0]), leaky(acc[1]), leaky(acc[2]), leaky(acc[3]));
        ((float4*)out)[(size_t)n * 32 + sub4 * 2 + 1] =
            make_float4(leaky(acc[4]), leaky(acc[5]), leaky(acc[6]), leaky(acc[7]));
    }
}

// ---------------------------------------------------------------------------
extern "C" void kernel_launch(void* const* d_in, const int* in_sizes, int n_in,
                              void* d_out, int out_size, void* d_ws, size_t ws_size,
                              hipStream_t stream)
{
    const void* x  = d_in[0];
    const void* ei = d_in[1];
    const void* Wq = d_in[2];
    const void* Wk = d_in[3];
    const void* Wl = d_in[4];
    const void* bl = d_in[5];
    float* out = (float*)d_out;   // reference output dtype = float32

    char* ws = (char*)d_ws;
    size_t off = 0;
    auto alloc = [&](size_t bytes) -> size_t {
        off = (off + 255) & ~(size_t)255;
        size_t o = off; off += bytes; return o;
    };
    const size_t o_flag  = alloc(256);        // flags + ovf_cnt + done live here
    const size_t o_wf    = alloc((size_t)W_TOTAL * sizeof(float));
    const size_t o_wbp   = alloc((size_t)PACKB_JOBS * sizeof(u32));     // 40 KB
    const size_t o_hq    = alloc((size_t)N_NODES * NHEADS * sizeof(float));
    const size_t o_kact  = alloc((size_t)N_NODES * NHEADS * sizeof(float));
    const size_t o_qagg  = alloc((size_t)N_NODES * NHEADS * sizeof(float));
    const size_t o_hproj = alloc((size_t)N_NODES * DIM * sizeof(u16));  // 12.8 MB
    const size_t o_deg   = alloc((size_t)N_NODES * sizeof(int));        // 200 KB
    const size_t o_ovfc  = alloc(256);                                  // ovf_cnt + done
    const size_t o_csr   = alloc((size_t)N_NODES * CAP * sizeof(u16));  // 6.4 MB
    const size_t o_ovf   = alloc((size_t)N_EDGES * sizeof(u32));        // 6.4 MB
    const size_t o_rc32  = alloc((size_t)N_EDGES * sizeof(u32));        // 6.4 MB
    const size_t o_sort  = alloc((size_t)N_EDGES * sizeof(u32));        // 6.4 MB
    const size_t o_hist  = alloc((size_t)SB * NB * sizeof(int));        // 1.6 MB
    const size_t o_btot  = alloc((size_t)NB * sizeof(int));
    const size_t o_btb   = alloc((size_t)(NB + 1) * sizeof(int));
    (void)ws_size;   // ~43 MB total, ws_size proven >= 45.9 MB in r7

    int*   flags   = (int*)(ws + o_flag);
    float* wf      = (float*)(ws + o_wf);
    u32*   wbp     = (u32*)(ws + o_wbp);
    float* h_q     = (float*)(ws + o_hq);
    float* k_act   = (float*)(ws + o_kact);
    float* q_agg   = (float*)(ws + o_qagg);
    u16*   h_projb = (u16*)(ws + o_hproj);
    int*   deg     = (int*)(ws + o_deg);
    int*   ovf_cnt = (int*)(ws + o_ovfc);
    int*   done    = (int*)(ws + o_ovfc) + 16;   // separate 64B line
    u16*   csr_col = (u16*)(ws + o_csr);
    u32*   ovf     = (u32*)(ws + o_ovf);
    u32*   rc32    = (u32*)(ws + o_rc32);
    u32*   sorted  = (u32*)(ws + o_sort);
    int*   hist    = (int*)(ws + o_hist);
    int*   btot    = (int*)(ws + o_btot);
    int*   btbase  = (int*)(ws + o_btb);

    // canon: flags + ovf_cnt=0 + done=0 + wf + packed B image
    canon_w_kernel<<<(W_TOTAL + PACKB_JOBS + 255) / 256, 256, 0, stream>>>(
        x, ei, Wq, Wk, Wl, bl, flags, ovf_cnt, done, wf, wbp);
    // PACKED: proj (blocks 0-781) || hist (blocks 782-1293) — independent work
    proj_hist_kernel<<<PROJ_BLOCKS + SB, 256, 0, stream>>>(
        x, ei, flags, wf, wbp, h_projb, h_q, k_act, rc32, hist);
    // scanA with scanB folded in (last-block pattern)
    scanA_kernel<<<NB, 256, 0, stream>>>(hist, btot, btbase, done);
    scatter_kernel<<<SB, 256, 0, stream>>>(rc32, hist, btbase, sorted);
    slab_kernel<<<NB, 256, 0, stream>>>(sorted, btbase, h_q, deg, csr_col,
                                        ovf_cnt, ovf, q_agg);
    attn_kernel<<<N_NODES / 4, 256, 0, stream>>>(deg, csr_col, ovf_cnt, ovf,
                                                 k_act, q_agg, h_projb, out);
}

// Round 17
// 205.034 us; speedup vs baseline: 1.1631x; 1.1631x over previous
//
#include <hip/hip_runtime.h>
#include <cstdint>
#include <cstddef>

typedef unsigned short u16;
typedef unsigned int   u32;
typedef long long      i64;

#define N_NODES 50000
#define N_EDGES 1600000
#define DIM     128
#define NHEADS  4
#define NEG_SLOPE 0.2f
#define CAP     64          // per-node slab (max deg ~58 for Binom(1.6M,1/50k); exact ovf path)
#define NB      782         // buckets of 64 nodes: bucket = r >> 6 (50000/64 -> 782)
#define SB      512         // hist/scatter blocks; EPB = E/SB = 3125 exact
#define EPB     (N_EDGES / SB)
#define PROJ_BLOCKS ((N_NODES + 63) / 64)   // 782

typedef __attribute__((ext_vector_type(8))) short bf16x8;
typedef __attribute__((ext_vector_type(4))) float f32x4;

__device__ __forceinline__ float b2f(u16 u) {
    union { u32 u; float f; } v; v.u = ((u32)u) << 16; return v.f;
}
__device__ __forceinline__ float bflo(u32 w) {
    union { u32 u; float f; } v; v.u = w << 16; return v.f;
}
__device__ __forceinline__ float bfhi(u32 w) {
    union { u32 u; float f; } v; v.u = w & 0xffff0000u; return v.f;
}
__device__ __forceinline__ u16 f2b(float f) {
    union { float f; u32 u; } v; v.f = f;
    u32 u = v.u;
    u32 r = (u + 0x7fffu + ((u >> 16) & 1u)) >> 16;
    return (u16)r;
}
__device__ __forceinline__ float leaky(float v) {
    return v >= 0.f ? v : NEG_SLOPE * v;
}
// f=1: fp32 storage; f=0: packed bf16
__device__ __forceinline__ float fload(const void* p, int f, int idx) {
    return f ? ((const float*)p)[idx] : b2f(((const u16*)p)[idx]);
}
// edge_index stored (2, E) row-major: elem[e]=row_e, elem[E+e]=col_e
__device__ __forceinline__ int eload(const void* ei, int f64, int idx) {
    return f64 ? (int)((const i64*)ei)[idx] : ((const int*)ei)[idx];
}

// ---------------------------------------------------------------------------
// storage detection helpers (validated; run per-block in canon)
// ---------------------------------------------------------------------------
__device__ __forceinline__ int fp32_vote(const u32* p, int K, int lane) {
    int bad = 0;
    for (int i = lane; i < K; i += 64) {
        const u32 w = p[i];
        const u16 lo = (u16)(w & 0xffff);
        const float v = b2f(lo);
        if (lo == 0 || !(fabsf(v) < 1e4f)) ++bad;
    }
    #pragma unroll
    for (int off = 32; off > 0; off >>= 1) bad += __shfl_down(bad, off);
    return bad;
}

__device__ __forceinline__ void compute_flags(
    const u32* x, const u32* wq, const u32* wk, const u32* wl,
    const u32* bl, const u32* ei, int* lf)
{
    const int t = threadIdx.x;
    if (t < 64) {
        const int lane = t;
        int b;
        b = fp32_vote(x,  256, lane); if (lane == 0) lf[0] = (b > 64);
        b = fp32_vote(wq, 128, lane); if (lane == 0) lf[1] = (b > 32);
        b = fp32_vote(wk, 128, lane); if (lane == 0) lf[2] = (b > 32);
        b = fp32_vote(wl, 256, lane); if (lane == 0) lf[3] = (b > 64);
        b = fp32_vote(bl,  64, lane); if (lane == 0) lf[4] = (b > 16);
        int z = 0;
        for (int i = lane; i < 256; i += 64)
            if (ei[2 * i + 1] == 0) ++z;
        #pragma unroll
        for (int off = 32; off > 0; off >>= 1) z += __shfl_down(z, off);
        if (lane == 0) lf[5] = (z > 128);
    }
    __syncthreads();
}

// B-image layout helper: value of stacked-B row/col (row in [0,160))
__device__ __forceinline__ float bimg_val(
    int row, int col, const void* Wq, const void* Wk, const void* Wl,
    const int* lf)
{
    if (row < 128)      return fload(Wl, lf[3], row * 128 + col);
    if (row < 132)      return fload(Wq, lf[1], (row - 128) * 128 + col);
    if (row < 136)      return fload(Wk, lf[2], (row - 132) * 128 + col);
    if (row < 144)      return 0.f;
    if (row < 148) { const float w = fload(Wq, lf[1], (row - 144) * 128 + col);
                     return w - b2f(f2b(w)); }
    if (row < 152) { const float w = fload(Wk, lf[2], (row - 148) * 128 + col);
                     return w - b2f(f2b(w)); }
    return 0.f;
}

// ---------------------------------------------------------------------------
// K canon v3: detection + ovf_cnt zeroing folded in (validated r14/r15).
//   NOTE r16 lesson: do NOT add per-block device-scope __threadfence on this
//   chip — each one forces an XCD L2 writeback (non-coherent L2s, G16);
//   782 of them cost +33 us. Cross-kernel boundaries are the cheap fence.
// ---------------------------------------------------------------------------
#define W_TOTAL (512 + 512 + 16384 + 128)
#define PACKB_JOBS (160 * 64)            // u32 words of the B image
__global__ __launch_bounds__(256) void canon_w_kernel(
    const void* __restrict__ x,  const void* __restrict__ ei,
    const void* __restrict__ Wq, const void* __restrict__ Wk,
    const void* __restrict__ Wl, const void* __restrict__ bl,
    int* __restrict__ flags, int* __restrict__ ovf_cnt,
    float* __restrict__ wf, u32* __restrict__ wbp)
{
    __shared__ int lf[8];
    compute_flags((const u32*)x, (const u32*)Wq, (const u32*)Wk,
                  (const u32*)Wl, (const u32*)bl, (const u32*)ei, lf);
    const int i = blockIdx.x * 256 + threadIdx.x;
    if (blockIdx.x == 0 && threadIdx.x == 0) {
        #pragma unroll
        for (int k = 0; k < 6; ++k) flags[k] = lf[k];
        *ovf_cnt = 0;
    }
    if (i < W_TOTAL) {
        const void* src; int j, f;
        if (i < 512)         { src = Wq; j = i;         f = lf[1]; }
        else if (i < 1024)   { src = Wk; j = i - 512;   f = lf[2]; }
        else if (i < 17408)  { src = Wl; j = i - 1024;  f = lf[3]; }
        else                 { src = bl; j = i - 17408; f = lf[4]; }
        wf[i] = fload(src, f, j);
        return;
    }
    const int w = i - W_TOTAL;
    if (w >= PACKB_JOBS) return;
    const int row  = w >> 6;
    const int col0 = (w & 63) * 2;
    const float v0 = bimg_val(row, col0,     Wq, Wk, Wl, lf);
    const float v1 = bimg_val(row, col0 + 1, Wq, Wk, Wl, lf);
    const int scol0 = col0 ^ ((row & 7) << 3);
    wbp[row * 64 + (scol0 >> 1)] = (u32)f2b(v0) | ((u32)f2b(v1) << 16);
}

// ---------------------------------------------------------------------------
// K1+S1 PACKED: blocks [0, PROJ_BLOCKS) = MFMA proj; rest = hist+pack
//   (validated r15).
// ---------------------------------------------------------------------------
__global__ __launch_bounds__(256) void proj_hist_kernel(
    const void* __restrict__ x, const void* __restrict__ ei,
    const int* __restrict__ flags,
    const float* __restrict__ wf, const u32* __restrict__ wbp,
    u16* __restrict__ h_projb, float* __restrict__ h_q,
    float* __restrict__ k_act,
    u32* __restrict__ rc32, int* __restrict__ hist)
{
    __shared__ __align__(16) char smem[160 * 128 * 2];   // 40 KB, aliased
    const int t = threadIdx.x;

    if (blockIdx.x >= PROJ_BLOCKS) {
        // ---------------- hist branch ----------------
        int* h = (int*)smem;
        const int blk = blockIdx.x - PROJ_BLOCKS;
        for (int i = t; i < NB; i += 256) h[i] = 0;
        __syncthreads();
        const int fe = flags[5];
        const int e0 = blk * EPB;
        const int e1 = min(e0 + EPB, N_EDGES);
        for (int e = e0 + t; e < e1; e += 256) {
            const int r = eload(ei, fe, e);
            const int c = eload(ei, fe, N_EDGES + e);
            rc32[e] = ((u32)r << 16) | (u32)c;
            atomicAdd(&h[r >> 6], 1);
        }
        __syncthreads();
        for (int i = t; i < NB; i += 256) hist[blk * NB + i] = h[i];
        return;
    }

    // ---------------- proj branch (validated r12) ----------------
    u16* sB   = (u16*)smem;
    u32* sB32 = (u32*)smem;
    const int w  = t >> 6;
    const int l  = t & 63;
    const int lr = l & 15;               // row/col within 16-tile
    const int lg = l >> 4;               // k-group / m-group
    const int Mb = blockIdx.x * 64 + w * 16;
    const float* bl = wf + 17408;

    #pragma unroll 8
    for (int i = t; i < 160 * 64; i += 256) sB32[i] = wbp[i];
    __syncthreads();

    const int fx = flags[0];
    f32x4 acc[9];
    #pragma unroll
    for (int tt = 0; tt < 8; ++tt) {
        const float bias = bl[tt * 16 + lr];
        acc[tt][0] = bias; acc[tt][1] = bias; acc[tt][2] = bias; acc[tt][3] = bias;
    }
    acc[8][0] = 0.f; acc[8][1] = 0.f; acc[8][2] = 0.f; acc[8][3] = 0.f;

    const int arow = min(Mb + lr, N_NODES - 1);

    #pragma unroll
    for (int kk = 0; kk < 4; ++kk) {
        const int kbase = kk * 32 + lg * 8;
        bf16x8 ahi, alo;
        if (fx == 0) {
            ahi = *(const bf16x8*)((const u16*)x + (size_t)arow * 128 + kbase);
            #pragma unroll
            for (int i = 0; i < 8; ++i) alo[i] = 0;
        } else {
            const float* xf = (const float*)x + (size_t)arow * 128 + kbase;
            const float4 v0 = *(const float4*)xf;
            const float4 v1 = *(const float4*)(xf + 4);
            const float vv[8] = {v0.x, v0.y, v0.z, v0.w, v1.x, v1.y, v1.z, v1.w};
            #pragma unroll
            for (int i = 0; i < 8; ++i) {
                const u16 h = f2b(vv[i]);
                ahi[i] = (short)h;
                alo[i] = (short)f2b(vv[i] - b2f(h));
            }
        }
        #pragma unroll
        for (int tt = 0; tt < 9; ++tt) {
            const int row = tt * 16 + lr;
            const bf16x8 b = *(const bf16x8*)&sB[row * 128 + (kbase ^ ((row & 7) << 3))];
            acc[tt] = __builtin_amdgcn_mfma_f32_16x16x32_bf16(ahi, b, acc[tt], 0, 0, 0);
            if (fx)
                acc[tt] = __builtin_amdgcn_mfma_f32_16x16x32_bf16(alo, b, acc[tt], 0, 0, 0);
        }
        {   // qk lo-tile (rows 144-159) accumulates into acc[8]
            const int row = 144 + lr;
            const bf16x8 b9 = *(const bf16x8*)&sB[row * 128 + (kbase ^ ((row & 7) << 3))];
            acc[8] = __builtin_amdgcn_mfma_f32_16x16x32_bf16(ahi, b9, acc[8], 0, 0, 0);
        }
    }

    #pragma unroll
    for (int tt = 0; tt < 8; ++tt) {
        const int o = tt * 16 + lr;
        #pragma unroll
        for (int j = 0; j < 4; ++j) {
            const int n = Mb + lg * 4 + j;
            if (n < N_NODES) h_projb[(size_t)n * 128 + o] = f2b(acc[tt][j]);
        }
    }
    #pragma unroll
    for (int j = 0; j < 4; ++j) {
        const int n = Mb + lg * 4 + j;
        if (n < N_NODES) {
            if (lr < 4)      h_q[n * 4 + lr] = acc[8][j];
            else if (lr < 8) k_act[n * 4 + (lr - 4)] = leaky(acc[8][j]);
        }
    }
}

// ---------------------------------------------------------------------------
// S2 v2: per-bucket exclusive scan over the 512 block-counts, XCD-grouped
//   order g(j) (validated r12/r15). scanB kept as its own kernel — the
//   kernel boundary IS the cheap device-wide fence (r16 lesson).
// ---------------------------------------------------------------------------
__device__ __forceinline__ int gperm(int j) {
    return ((j & 63) << 3) | (j >> 6);
}
__global__ __launch_bounds__(256) void scanA_kernel(
    int* __restrict__ hist, int* __restrict__ btot)
{
    __shared__ int part[256];
    const int b = blockIdx.x;
    const int t = threadIdx.x;
    const int b0 = gperm(2 * t), b1 = gperm(2 * t + 1);
    const int v0 = hist[b0 * NB + b];
    const int v1 = hist[b1 * NB + b];
    part[t] = v0 + v1;
    __syncthreads();
    for (int off = 1; off < 256; off <<= 1) {
        const int v = (t >= off) ? part[t - off] : 0;
        __syncthreads();
        part[t] += v;
        __syncthreads();
    }
    const int pre = part[t] - (v0 + v1);
    hist[b0 * NB + b] = pre;
    hist[b1 * NB + b] = pre + v0;
    if (t == 255) btot[b] = part[255];
}

// ---------------------------------------------------------------------------
// S3: scan bucket totals -> bucket bases. 1 block (782 values).
// ---------------------------------------------------------------------------
__global__ __launch_bounds__(1024) void scanB_kernel(
    const int* __restrict__ btot, int* __restrict__ btbase)
{
    __shared__ int part[1024];
    const int t = threadIdx.x;
    const int v = (t < NB) ? btot[t] : 0;
    part[t] = v;
    __syncthreads();
    for (int off = 1; off < 1024; off <<= 1) {
        const int x = (t >= off) ? part[t - off] : 0;
        __syncthreads();
        part[t] += x;
        __syncthreads();
    }
    if (t < NB) btbase[t] = part[t] - v;
    if (t == NB - 1) btbase[NB] = part[t];
}

// ---------------------------------------------------------------------------
// S4: scatter to bucket-sorted array with EXACT precomputed offsets.
// ---------------------------------------------------------------------------
__global__ __launch_bounds__(256) void scatter_kernel(
    const u32* __restrict__ rc32, const int* __restrict__ hist,
    const int* __restrict__ btbase, u32* __restrict__ sorted)
{
    __shared__ int lbase[NB];
    const int t = threadIdx.x, blk = blockIdx.x;
    for (int i = t; i < NB; i += 256)
        lbase[i] = btbase[i] + hist[blk * NB + i];
    __syncthreads();
    const int e0 = blk * EPB;
    const int e1 = min(e0 + EPB, N_EDGES);
    for (int e = e0 + t; e < e1; e += 256) {
        const u32 rc = rc32[e];
        const int p = atomicAdd(&lbase[rc >> 22], 1);   // bucket = r>>6 = rc>>22
        sorted[p] = rc;
    }
}

// ---------------------------------------------------------------------------
// S5 v3: per-bucket slab build + fused q_agg (post-fill shfl gather,
//   validated r14/r15).
// ---------------------------------------------------------------------------
__global__ __launch_bounds__(256) void slab_kernel(
    const u32* __restrict__ sorted, const int* __restrict__ btbase,
    const float* __restrict__ h_q,
    int* __restrict__ deg, u16* __restrict__ csr_col,
    int* __restrict__ ovf_cnt, u32* __restrict__ ovf,
    float* __restrict__ q_agg)
{
    __shared__ int   cnt[64];
    __shared__ float qov[64][4];         // overflow-only accumulator (rare)
    const int t = threadIdx.x, b = blockIdx.x;
    if (t < 64) {
        cnt[t] = 0;
        qov[t][0] = 0.f; qov[t][1] = 0.f; qov[t][2] = 0.f; qov[t][3] = 0.f;
    }
    __syncthreads();
    const int s0 = btbase[b], s1 = btbase[b + 1];
    for (int i = s0 + t; i < s1; i += 256) {
        const u32 rc = sorted[i];
        const int r  = (int)(rc >> 16);
        const int c  = (int)(rc & 0xffffu);
        const int rl = r & 63;
        const int p = atomicAdd(&cnt[rl], 1);
        if (p < CAP) {
            csr_col[r * CAP + p] = (u16)c;
        } else {                          // rare-path: exact
            const int k = atomicAdd(ovf_cnt, 1);
            ovf[k] = rc;
            const float4 q = ((const float4*)h_q)[c];
            atomicAdd(&qov[rl][0], q.x);
            atomicAdd(&qov[rl][1], q.y);
            atomicAdd(&qov[rl][2], q.z);
            atomicAdd(&qov[rl][3], q.w);
        }
    }
    __syncthreads();
    // post-fill per-node q_agg gather: 4 threads per node, shfl-reduce
    const int nl = t >> 2;               // node-local 0..63
    const int ql = t & 3;                // quarter within node group
    const int n  = b * 64 + nl;
    float sx = 0.f, sy = 0.f, sz = 0.f, sw = 0.f;
    int d = 0;
    if (n < N_NODES) {
        d = cnt[nl];
        const int prim = min(d, CAP);
        for (int j = ql; j < prim; j += 4) {
            const int c = csr_col[n * CAP + j];
            const float4 q = ((const float4*)h_q)[c];
            sx += q.x; sy += q.y; sz += q.z; sw += q.w;
        }
    }
    sx += __shfl_down(sx, 2); sx += __shfl_down(sx, 1);
    sy += __shfl_down(sy, 2); sy += __shfl_down(sy, 1);
    sz += __shfl_down(sz, 2); sz += __shfl_down(sz, 1);
    sw += __shfl_down(sw, 2); sw += __shfl_down(sw, 1);
    if (n < N_NODES && ql == 0) {
        deg[n] = d;
        ((float4*)q_agg)[n] = make_float4(
            sx + qov[nl][0], sy + qov[nl][1], sz + qov[nl][2], sw + qov[nl][3]);
    }
}

// ---------------------------------------------------------------------------
// K7: fused softmax + weighted aggregation -> out fp32 (validated r6-r15)
// ---------------------------------------------------------------------------
__global__ __launch_bounds__(256) void attn_kernel(
    const int* __restrict__ deg_a, const u16* __restrict__ csr_col,
    const int* __restrict__ ovf_cnt, const u32* __restrict__ ovf,
    const float* __restrict__ k_act, const float* __restrict__ q_agg,
    const u16* __restrict__ h_projb, float* __restrict__ out)
{
    const int wave = threadIdx.x >> 6, lane = threadIdx.x & 63;
    const int n = blockIdx.x * 4 + wave;
    if (n >= N_NODES) return;
    const int deg = deg_a[n];
    const int prim = min(deg, CAP);
    const float4 k4 = ((const float4*)k_act)[n];

    // ---- pass A: scores (slot = lane), split max/sum reduction ----
    int cA = 0;
    float sA0 = -1e30f, sA1 = -1e30f, sA2 = -1e30f, sA3 = -1e30f;
    if (lane < prim) {
        cA = csr_col[n * CAP + lane];
        const float4 q = ((const float4*)q_agg)[cA];
        sA0 = k4.x * q.x; sA1 = k4.y * q.y;
        sA2 = k4.z * q.z; sA3 = k4.w * q.w;
    }
    float m0 = sA0, m1 = sA1, m2 = sA2, m3 = sA3;
    const int ovf_n = (deg > CAP) ? *ovf_cnt : 0;
    for (int i = lane; i < ovf_n; i += 64) {
        const u32 pk = ovf[i];
        if ((int)(pk >> 16) != n) continue;
        const float4 q = ((const float4*)q_agg)[pk & 0xffffu];
        m0 = fmaxf(m0, k4.x * q.x); m1 = fmaxf(m1, k4.y * q.y);
        m2 = fmaxf(m2, k4.z * q.z); m3 = fmaxf(m3, k4.w * q.w);
    }
    #pragma unroll
    for (int off = 32; off > 0; off >>= 1) {
        m0 = fmaxf(m0, __shfl_xor(m0, off));
        m1 = fmaxf(m1, __shfl_xor(m1, off));
        m2 = fmaxf(m2, __shfl_xor(m2, off));
        m3 = fmaxf(m3, __shfl_xor(m3, off));
    }
    const float e0 = __expf(sA0 - m0), e1 = __expf(sA1 - m1);
    const float e2 = __expf(sA2 - m2), e3 = __expf(sA3 - m3);
    float u0 = e0, u1 = e1, u2 = e2, u3 = e3;
    for (int i = lane; i < ovf_n; i += 64) {
        const u32 pk = ovf[i];
        if ((int)(pk >> 16) != n) continue;
        const float4 q = ((const float4*)q_agg)[pk & 0xffffu];
        u0 += __expf(k4.x * q.x - m0); u1 += __expf(k4.y * q.y - m1);
        u2 += __expf(k4.z * q.z - m2); u3 += __expf(k4.w * q.w - m3);
    }
    #pragma unroll
    for (int off = 32; off > 0; off >>= 1) {
        u0 += __shfl_xor(u0, off); u1 += __shfl_xor(u1, off);
        u2 += __shfl_xor(u2, off); u3 += __shfl_xor(u3, off);
    }
    const float r0 = 0.25f / (u0 + 1e-8f), r1 = 0.25f / (u1 + 1e-8f);
    const float r2 = 0.25f / (u2 + 1e-8f), r3 = 0.25f / (u3 + 1e-8f);
    const float a_s = e0 * r0 + e1 * r1 + e2 * r2 + e3 * r3;  // lane's alpha

    // ---- pass B: quad-edge broadcast accumulate ----
    const int sub4 = lane & 15;          // dim group: dims 8*sub4 .. 8*sub4+7
    const int eh4  = lane >> 4;          // which edge of the quad (0..3)
    float acc[8] = {0.f, 0.f, 0.f, 0.f, 0.f, 0.f, 0.f, 0.f};
    const uint4* hp4 = (const uint4*)h_projb;   // row stride = 16 uint4 (256 B)

    #pragma unroll 4
    for (int j = 0; j < prim; j += 4) {
        const int   c = __shfl(cA,  j + eh4);
        const float a = __shfl(a_s, j + eh4);
        const uint4 w = hp4[(size_t)c * 16 + sub4];
        acc[0] = fmaf(a, bflo(w.x), acc[0]);
        acc[1] = fmaf(a, bfhi(w.x), acc[1]);
        acc[2] = fmaf(a, bflo(w.y), acc[2]);
        acc[3] = fmaf(a, bfhi(w.y), acc[3]);
        acc[4] = fmaf(a, bflo(w.z), acc[4]);
        acc[5] = fmaf(a, bfhi(w.z), acc[5]);
        acc[6] = fmaf(a, bflo(w.w), acc[6]);
        acc[7] = fmaf(a, bfhi(w.w), acc[7]);
    }
    for (int base = 0; base < ovf_n; base += 64) {
        const int i = base + lane;
        int   c_s = 0;
        float a_v = 0.f;
        if (i < ovf_n) {
            const u32 pk = ovf[i];
            if ((int)(pk >> 16) == n) {
                c_s = (int)(pk & 0xffffu);
                const float4 q = ((const float4*)q_agg)[c_s];
                a_v = __expf(k4.x * q.x - m0) * r0 + __expf(k4.y * q.y - m1) * r1
                    + __expf(k4.z * q.z - m2) * r2 + __expf(k4.w * q.w - m3) * r3;
            }
        }
        const int cnt = min(64, ovf_n - base);
        for (int j = 0; j < cnt; j += 4) {
            const int   jj = j + eh4;
            const int   c = __shfl(c_s, jj);      // lanes past cnt hold a_v=0
            const float a = __shfl(a_v, jj);
            const uint4 w = hp4[(size_t)c * 16 + sub4];
            acc[0] = fmaf(a, bflo(w.x), acc[0]);
            acc[1] = fmaf(a, bfhi(w.x), acc[1]);
            acc[2] = fmaf(a, bflo(w.y), acc[2]);
            acc[3] = fmaf(a, bfhi(w.y), acc[3]);
            acc[4] = fmaf(a, bflo(w.z), acc[4]);
            acc[5] = fmaf(a, bfhi(w.z), acc[5]);
            acc[6] = fmaf(a, bflo(w.w), acc[6]);
            acc[7] = fmaf(a, bfhi(w.w), acc[7]);
        }
    }
    #pragma unroll
    for (int d = 0; d < 8; ++d) {
        acc[d] += __shfl_down(acc[d], 32);
        acc[d] += __shfl_down(acc[d], 16);
    }
    if (eh4 == 0) {
        ((float4*)out)[(size_t)n * 32 + sub4 * 2] =
            make_float4(leaky(acc[0]), leaky(acc[1]), leaky(acc[2]), leaky(acc[3]));
        ((float4*)out)[(size_t)n * 32 + sub4 * 2 + 1] =
            make_float4(leaky(acc[4]), leaky(acc[5]), leaky(acc[6]), leaky(acc[7]));
    }
}

// ---------------------------------------------------------------------------
extern "C" void kernel_launch(void* const* d_in, const int* in_sizes, int n_in,
                              void* d_out, int out_size, void* d_ws, size_t ws_size,
                              hipStream_t stream)
{
    const void* x  = d_in[0];
    const void* ei = d_in[1];
    const void* Wq = d_in[2];
    const void* Wk = d_in[3];
    const void* Wl = d_in[4];
    const void* bl = d_in[5];
    float* out = (float*)d_out;   // reference output dtype = float32

    char* ws = (char*)d_ws;
    size_t off = 0;
    auto alloc = [&](size_t bytes) -> size_t {
        off = (off + 255) & ~(size_t)255;
        size_t o = off; off += bytes; return o;
    };
    const size_t o_flag  = alloc(256);
    const size_t o_wf    = alloc((size_t)W_TOTAL * sizeof(float));
    const size_t o_wbp   = alloc((size_t)PACKB_JOBS * sizeof(u32));     // 40 KB
    const size_t o_hq    = alloc((size_t)N_NODES * NHEADS * sizeof(float));
    const size_t o_kact  = alloc((size_t)N_NODES * NHEADS * sizeof(float));
    const size_t o_qagg  = alloc((size_t)N_NODES * NHEADS * sizeof(float));
    const size_t o_hproj = alloc((size_t)N_NODES * DIM * sizeof(u16));  // 12.8 MB
    const size_t o_deg   = alloc((size_t)N_NODES * sizeof(int));        // 200 KB
    const size_t o_ovfc  = alloc(256);                                  // zeroed by canon
    const size_t o_csr   = alloc((size_t)N_NODES * CAP * sizeof(u16));  // 6.4 MB
    const size_t o_ovf   = alloc((size_t)N_EDGES * sizeof(u32));        // 6.4 MB
    const size_t o_rc32  = alloc((size_t)N_EDGES * sizeof(u32));        // 6.4 MB
    const size_t o_sort  = alloc((size_t)N_EDGES * sizeof(u32));        // 6.4 MB
    const size_t o_hist  = alloc((size_t)SB * NB * sizeof(int));        // 1.6 MB
    const size_t o_btot  = alloc((size_t)NB * sizeof(int));
    const size_t o_btb   = alloc((size_t)(NB + 1) * sizeof(int));
    (void)ws_size;   // ~43 MB total, ws_size proven >= 45.9 MB in r7

    int*   flags   = (int*)(ws + o_flag);
    float* wf      = (float*)(ws + o_wf);
    u32*   wbp     = (u32*)(ws + o_wbp);
    float* h_q     = (float*)(ws + o_hq);
    float* k_act   = (float*)(ws + o_kact);
    float* q_agg   = (float*)(ws + o_qagg);
    u16*   h_projb = (u16*)(ws + o_hproj);
    int*   deg     = (int*)(ws + o_deg);
    int*   ovf_cnt = (int*)(ws + o_ovfc);
    u16*   csr_col = (u16*)(ws + o_csr);
    u32*   ovf     = (u32*)(ws + o_ovf);
    u32*   rc32    = (u32*)(ws + o_rc32);
    u32*   sorted  = (u32*)(ws + o_sort);
    int*   hist    = (int*)(ws + o_hist);
    int*   btot    = (int*)(ws + o_btot);
    int*   btbase  = (int*)(ws + o_btb);

    // canon: flags + ovf_cnt=0 + wf + packed B image
    canon_w_kernel<<<(W_TOTAL + PACKB_JOBS + 255) / 256, 256, 0, stream>>>(
        x, ei, Wq, Wk, Wl, bl, flags, ovf_cnt, wf, wbp);
    // PACKED: proj (blocks 0-781) || hist (blocks 782-1293) — independent work
    proj_hist_kernel<<<PROJ_BLOCKS + SB, 256, 0, stream>>>(
        x, ei, flags, wf, wbp, h_projb, h_q, k_act, rc32, hist);
    scanA_kernel<<<NB, 256, 0, stream>>>(hist, btot);
    scanB_kernel<<<1, 1024, 0, stream>>>(btot, btbase);
    scatter_kernel<<<SB, 256, 0, stream>>>(rc32, hist, btbase, sorted);
    slab_kernel<<<NB, 256, 0, stream>>>(sorted, btbase, h_q, deg, csr_col,
                                        ovf_cnt, ovf, q_agg);
    attn_kernel<<<N_NODES / 4, 256, 0, stream>>>(deg, csr_col, ovf_cnt, ovf,
                                                 k_act, q_agg, h_projb, out);
}